// Round 9
// baseline (52.385 us; speedup 1.0000x reference)
//
#include <hip/hip_runtime.h>

#define NTOK 16384
#define NC 2048
#define C4 512            // float4 per row
#define NE 8
#define TPB 512           // 8 waves
#define TOKW 4            // tokens per wave
#define TOK_PER_BLOCK 32  // 8 waves x 4 tokens
#define NBLK (NTOK / TOK_PER_BLOCK)   // 512 = 2 blocks/CU exactly

// Lore (R1-R8):
//  - VGPR cap = 256 / launch_bounds_arg2 (measured: (256,2)->128, (256,4)->64,
//    (512,4)->64). Must keep cap >= ~110 live regs or acc[] spills to scratch
//    (R2/R3/R5: 33-300MB scratch traffic, 2-4x slowdown).
//  - acc as separately-named arrays (acc0..acc3), NOT acc[4][8] (R5 spill).
//  - #pragma unroll 2 on k-loop; full unroll hoists all loads -> spill (R4).
//  - R6==R8 (43us) though gate traffic differed 2x -> bound by L1/TA pipe on
//    combined x+gate stream. Fix: gate via LDS (DS pipe), x via L1 (TA pipe).
__global__ __launch_bounds__(TPB, 2) void router_kernel(
    const float* __restrict__ x, const float* __restrict__ gw,
    float* __restrict__ out, float* __restrict__ ws) {
    __shared__ float4 s_gw[NE * C4];   // 64 KB -> 2 blocks/CU
    __shared__ float s_psum[NE];
    __shared__ float s_cnt[NE];

    const int tid = threadIdx.x;
    if (tid < NE) { s_psum[tid] = 0.0f; s_cnt[tid] = 0.0f; }

    // stage gate -> LDS once per block (64 MB total from L2/L3, off critical path)
    const float4* gw4 = (const float4*)gw;
    #pragma unroll
    for (int i = tid; i < NE * C4; i += TPB) s_gw[i] = gw4[i];
    __syncthreads();

    const int wave = tid >> 6;
    const int lane = tid & 63;
    const float4* x4 = (const float4*)x;
    const int t0 = blockIdx.x * TOK_PER_BLOCK + wave * TOKW;

    float* out_w = out;               // weights [N,2]
    float* out_i = out + 2 * NTOK;    // indices [N,2] stored as float

    float acc0[NE], acc1[NE], acc2[NE], acc3[NE];
    #pragma unroll
    for (int e = 0; e < NE; ++e) { acc0[e] = 0.0f; acc1[e] = 0.0f; acc2[e] = 0.0f; acc3[e] = 0.0f; }

    #pragma unroll 2
    for (int k = 0; k < 8; ++k) {
        const int idx = lane + k * 64;
        const float4 xv0 = x4[(size_t)(t0 + 0) * C4 + idx];   // TA pipe, coalesced 1KB
        const float4 xv1 = x4[(size_t)(t0 + 1) * C4 + idx];
        const float4 xv2 = x4[(size_t)(t0 + 2) * C4 + idx];
        const float4 xv3 = x4[(size_t)(t0 + 3) * C4 + idx];
        #pragma unroll
        for (int e = 0; e < NE; ++e) {
            const float4 wv = s_gw[e * C4 + idx];             // DS pipe, conflict-free
            acc0[e] += xv0.x * wv.x + xv0.y * wv.y + xv0.z * wv.z + xv0.w * wv.w;
            acc1[e] += xv1.x * wv.x + xv1.y * wv.y + xv1.z * wv.z + xv1.w * wv.w;
            acc2[e] += xv2.x * wv.x + xv2.y * wv.y + xv2.z * wv.z + xv2.w * wv.w;
            acc3[e] += xv3.x * wv.x + xv3.y * wv.y + xv3.z * wv.z + xv3.w * wv.w;
        }
    }

    // butterfly reduce over 64 lanes: every lane ends with full sums
    #pragma unroll
    for (int off = 32; off >= 1; off >>= 1) {
        #pragma unroll
        for (int e = 0; e < NE; ++e) {
            acc0[e] += __shfl_xor(acc0[e], off, 64);
            acc1[e] += __shfl_xor(acc1[e], off, 64);
            acc2[e] += __shfl_xor(acc2[e], off, 64);
            acc3[e] += __shfl_xor(acc3[e], off, 64);
        }
    }

    // every lane processes token (lane&3) -- static select chain (rule #20)
    const int t = lane & 3;
    float l[NE];
    #pragma unroll
    for (int e = 0; e < NE; ++e) {
        float v = acc0[e];
        v = (t == 1) ? acc1[e] : v;
        v = (t == 2) ? acc2[e] : v;
        v = (t == 3) ? acc3[e] : v;
        l[e] = v;
    }

    float mx = l[0];
    #pragma unroll
    for (int e = 1; e < NE; ++e) mx = fmaxf(mx, l[e]);
    float p[NE];
    float s = 0.0f;
    #pragma unroll
    for (int e = 0; e < NE; ++e) { p[e] = expf(l[e] - mx); s += p[e]; }
    const float inv = 1.0f / s;
    #pragma unroll
    for (int e = 0; e < NE; ++e) p[e] *= inv;

    // top-2, ties -> lower index (matches jax.lax.top_k)
    int i0 = 0; float p0 = p[0];
    #pragma unroll
    for (int e = 1; e < NE; ++e) if (p[e] > p0) { p0 = p[e]; i0 = e; }
    int i1 = (i0 == 0) ? 1 : 0; float p1 = p[i1];
    #pragma unroll
    for (int e = 0; e < NE; ++e)
        if (e != i0 && p[e] > p1) { p1 = p[e]; i1 = e; }

    if (lane < TOKW) {
        const int token = t0 + lane;
        const float wsum = p0 + p1;
        out_w[2 * token]     = p0 / wsum;
        out_w[2 * token + 1] = p1 / wsum;
        out_i[2 * token]     = (float)i0;
        out_i[2 * token + 1] = (float)i1;

        #pragma unroll
        for (int e = 0; e < NE; ++e) atomicAdd(&s_psum[e], p[e]);
        atomicAdd(&s_cnt[i0], 1.0f);
        atomicAdd(&s_cnt[i1], 1.0f);
    }

    __syncthreads();
    // non-atomic per-block partials -> no zero-init kernel needed
    if (tid < NE)          ws[blockIdx.x * 16 + tid] = s_psum[tid];
    else if (tid < 2 * NE) ws[blockIdx.x * 16 + tid] = s_cnt[tid - NE];
}

__global__ void finalize_kernel(const float* __restrict__ ws,
                                float* __restrict__ out) {
    __shared__ float red[16];
    const int tid = threadIdx.x;   // 1024 threads
    if (tid < 16) red[tid] = 0.0f;
    __syncthreads();
    const int i = tid & 15;
    float sum = 0.0f;
    for (int b = (tid >> 4); b < NBLK; b += 64)
        sum += ws[b * 16 + i];
    atomicAdd(&red[i], sum);
    __syncthreads();
    if (tid == 0) {
        float aux = 0.0f;
        #pragma unroll
        for (int e = 0; e < NE; ++e)
            aux += (red[NE + e] * (1.0f / NTOK)) * (red[e] * (1.0f / NTOK));
        out[4 * NTOK] = (float)NE * aux;
    }
}

extern "C" void kernel_launch(void* const* d_in, const int* in_sizes, int n_in,
                              void* d_out, int out_size, void* d_ws, size_t ws_size,
                              hipStream_t stream) {
    const float* x  = (const float*)d_in[0];   // [4,4096,2048] f32
    const float* gw = (const float*)d_in[1];   // [8,2048] f32
    float* out = (float*)d_out;                // weights[N,2] | indices[N,2] | aux
    float* ws  = (float*)d_ws;                 // per-block partials [NBLK][16]

    router_kernel<<<NBLK, TPB, 0, stream>>>(x, gw, out, ws);
    finalize_kernel<<<1, 1024, 0, stream>>>(ws, out);
}